// Round 2
// baseline (234.295 us; speedup 1.0000x reference)
//
#include <hip/hip_runtime.h>
#include <hip/hip_bf16.h>
#include <stdint.h>

// out[e,o] = relu( sum_d (emb[src[e],d] + emb[dst[e],d]) * W[o,d] + b[o] )
// E = 600000, D_IN = D_OUT = 128.
//
// R2 design: persistent blocks. W (bf16, swizzled) staged to LDS once per
// block; grid-stride loop over 64-edge tiles with NO barriers: each wave
// gathers its MFMA A-fragments directly global->reg (lanes {lr,lr+16,lr+32,
// lr+48} cover one contiguous 64B line of an edge row per k-step), converts
// fp32-add->bf16 in-reg, 32 MFMAs vs LDS-resident W, bias+relu, store.

using bf16x8 = __attribute__((ext_vector_type(8))) __bf16;
using f32x4  = __attribute__((ext_vector_type(4))) float;
using u16x8  = __attribute__((ext_vector_type(8))) unsigned short;
using u16x4  = __attribute__((ext_vector_type(4))) unsigned short;

static __device__ __forceinline__ unsigned short f2b(float f) {
    return __builtin_bit_cast(unsigned short, (__bf16)f);   // RNE fp32->bf16
}
static __device__ __forceinline__ float b2f(unsigned short u) {
    return __builtin_bit_cast(float, (unsigned int)u << 16); // exact bf16->fp32
}

// ---- prep: fp32 -> bf16 for node table and W (into d_ws) ----
__global__ void prep_cvt(const float* __restrict__ nodes,
                         const float* __restrict__ W,
                         unsigned short* __restrict__ nodes_b,
                         unsigned short* __restrict__ W_b,
                         int n_node4, int n_w4) {
    int i = blockIdx.x * blockDim.x + threadIdx.x;
    int stride = gridDim.x * blockDim.x;
    int total = n_node4 + n_w4;
    for (; i < total; i += stride) {
        const float4* src; unsigned short* dst; int j;
        if (i < n_node4) { src = (const float4*)nodes; dst = nodes_b; j = i; }
        else             { src = (const float4*)W;     dst = W_b;     j = i - n_node4; }
        float4 v = src[j];
        u16x4 r;
        r[0] = f2b(v.x); r[1] = f2b(v.y); r[2] = f2b(v.z); r[3] = f2b(v.w);
        *(u16x4*)&dst[(size_t)j * 4] = r;
    }
}

// Block: 256 thr (4 waves). Wave w owns edges [tile*64 + w*16, +16).
// W LDS tile XOR-swizzled (elem ^= (row&7)<<3) to kill the D=128 bank conflict.
template<int BSRC>
__global__ __launch_bounds__(256, 4) void edge_linear(
    const float* __restrict__ nodes_f,
    const unsigned short* __restrict__ nodes_b,
    const int* __restrict__ e_src,
    const int* __restrict__ e_dst,
    const float* __restrict__ Wf,
    const unsigned short* __restrict__ Wb,
    const float* __restrict__ bias,
    float* __restrict__ out,
    int E, int ntiles)
{
    __shared__ __align__(16) unsigned short Wt[128 * 128];  // 32 KiB
    const int tid = threadIdx.x;

    // stage W once (bf16, swizzled): B[k=d][n=o] = W[o][d]
    #pragma unroll
    for (int j = 0; j < 8; ++j) {
        int idx = j * 256 + tid;      // 2048 chunks of 8 elems
        int o = idx >> 4;             // output channel (row)
        int c = idx & 15;             // 8-elem chunk within row
        int elem = o * 128 + c * 8;
        int sw = elem ^ ((o & 7) << 3);
        if (BSRC) {
            *(u16x8*)&Wt[sw] = *(const u16x8*)&Wb[elem];
        } else {
            const float4* wp = (const float4*)&Wf[elem];
            float4 a = wp[0], b4 = wp[1];
            u16x8 r;
            r[0] = f2b(a.x);  r[1] = f2b(a.y);  r[2] = f2b(a.z);  r[3] = f2b(a.w);
            r[4] = f2b(b4.x); r[5] = f2b(b4.y); r[6] = f2b(b4.z); r[7] = f2b(b4.w);
            *(u16x8*)&Wt[sw] = r;
        }
    }
    __syncthreads();   // the only barrier in the kernel

    const int wave = tid >> 6;
    const int lane = tid & 63;
    const int lr = lane & 15;   // A row (edge) / B col within fragment
    const int lg = lane >> 4;   // k-group: k-offset = lg*8 within 32-k fragment

    float bv[8];
    #pragma unroll
    for (int n = 0; n < 8; ++n) bv[n] = bias[n * 16 + lr];

    for (int tile = blockIdx.x; tile < ntiles; tile += gridDim.x) {
        const int e0 = tile * 64 + wave * 16;
        int eg = e0 + lr; if (eg >= E) eg = E - 1;
        const int s = e_src[eg];
        const int d = e_dst[eg];

        f32x4 acc[8];
        #pragma unroll
        for (int n = 0; n < 8; ++n) acc[n] = (f32x4){0.f, 0.f, 0.f, 0.f};

        if (BSRC) {
            // gather all 8 fragments (src+dst x 4 k-steps), 16B each
            const u16x8* sp = (const u16x8*)&nodes_b[(size_t)s * 128 + lg * 8];
            const u16x8* dp = (const u16x8*)&nodes_b[(size_t)d * 128 + lg * 8];
            u16x8 sv[4], dv[4];
            #pragma unroll
            for (int ks = 0; ks < 4; ++ks) { sv[ks] = sp[ks * 4]; dv[ks] = dp[ks * 4]; }

            #pragma unroll
            for (int ks = 0; ks < 4; ++ks) {
                bf16x8 af;
                #pragma unroll
                for (int q = 0; q < 8; ++q)
                    af[q] = (__bf16)(b2f(sv[ks][q]) + b2f(dv[ks][q]));
                #pragma unroll
                for (int n = 0; n < 8; ++n) {
                    const int o = n * 16 + lr;
                    bf16x8 bf = *(const bf16x8*)&Wt[(o * 128 + ks * 32 + lg * 8) ^ ((o & 7) << 3)];
                    acc[n] = __builtin_amdgcn_mfma_f32_16x16x32_bf16(af, bf, acc[n], 0, 0, 0);
                }
            }
        } else {
            // fp32 fallback: 2x float4 per node per k-step
            const float4* spf = (const float4*)&nodes_f[(size_t)s * 128 + lg * 8];
            const float4* dpf = (const float4*)&nodes_f[(size_t)d * 128 + lg * 8];
            float4 sva[4][2], dva[4][2];
            #pragma unroll
            for (int ks = 0; ks < 4; ++ks) {
                sva[ks][0] = spf[ks * 8]; sva[ks][1] = spf[ks * 8 + 1];
                dva[ks][0] = dpf[ks * 8]; dva[ks][1] = dpf[ks * 8 + 1];
            }
            #pragma unroll
            for (int ks = 0; ks < 4; ++ks) {
                bf16x8 af;
                const float* sf = (const float*)&sva[ks][0];
                const float* df = (const float*)&dva[ks][0];
                #pragma unroll
                for (int q = 0; q < 8; ++q)
                    af[q] = (__bf16)(sf[q] + df[q]);
                #pragma unroll
                for (int n = 0; n < 8; ++n) {
                    const int o = n * 16 + lr;
                    bf16x8 bf = *(const bf16x8*)&Wt[(o * 128 + ks * 32 + lg * 8) ^ ((o & 7) << 3)];
                    acc[n] = __builtin_amdgcn_mfma_f32_16x16x32_bf16(af, bf, acc[n], 0, 0, 0);
                }
            }
        }

        // epilogue: bias + relu + store. C/D map: col = lane&15, row = 4*lg+reg.
        const int er0 = e0 + lg * 4;
        #pragma unroll
        for (int n = 0; n < 8; ++n) {
            #pragma unroll
            for (int j2 = 0; j2 < 4; ++j2) {
                const int e = er0 + j2;
                if (e < E) {
                    float v = acc[n][j2] + bv[n];
                    out[(size_t)e * 128 + n * 16 + lr] = v > 0.f ? v : 0.f;
                }
            }
        }
    }
}

extern "C" void kernel_launch(void* const* d_in, const int* in_sizes, int n_in,
                              void* d_out, int out_size, void* d_ws, size_t ws_size,
                              hipStream_t stream) {
    const float* nodes = (const float*)d_in[0];
    const int*   ei    = (const int*)d_in[1];     // [2][E] int32: row0=src, row1=dst
    const float* W     = (const float*)d_in[2];   // [128][128] fp32, row-major [o][d]
    const float* bias  = (const float*)d_in[3];   // [128] fp32
    float* out = (float*)d_out;

    const int n_node = in_sizes[0];               // 50000*128
    const int E      = in_sizes[1] / 2;           // 600000
    const int n_w    = in_sizes[2];               // 128*128

    const size_t node_bytes = (size_t)n_node * 2;
    const size_t need = node_bytes + (size_t)n_w * 2;
    const int ntiles = (E + 63) / 64;             // 9375
    int blocks = ntiles < 1024 ? ntiles : 1024;   // 4 blocks/CU, persistent

    if (ws_size >= need) {
        unsigned short* nodes_b = (unsigned short*)d_ws;
        unsigned short* W_b = (unsigned short*)((char*)d_ws + node_bytes);
        int n4 = n_node / 4, w4 = n_w / 4;
        int pgrid = (n4 + w4 + 255) / 256;
        if (pgrid > 2048) pgrid = 2048;
        prep_cvt<<<pgrid, 256, 0, stream>>>(nodes, W, nodes_b, W_b, n4, w4);
        edge_linear<1><<<blocks, 256, 0, stream>>>(nodes, nodes_b, ei, ei + E,
                                                   W, W_b, bias, out, E, ntiles);
    } else {
        edge_linear<0><<<blocks, 256, 0, stream>>>(nodes, nullptr, ei, ei + E,
                                                   W, nullptr, bias, out, E, ntiles);
    }
}

// Round 3
// 120.864 us; speedup vs baseline: 1.9385x; 1.9385x over previous
//
#include <hip/hip_runtime.h>
#include <hip/hip_bf16.h>
#include <stdint.h>

// out[e,o] = relu( sum_d (emb[src[e],d] + emb[dst[e],d]) * W[o,d] + b[o] )
// E = 600000, D_IN = D_OUT = 128.
//
// R3: persistent blocks; W (bf16, XOR-swizzled) in LDS once; per 64-edge tile
// cooperative gather (16 lanes read one contiguous 256-B node row) + fp32 add
// -> bf16 LDS tile; MFMA vs W; bias+relu; NON-TEMPORAL stores so the 307 MB
// write stream doesn't evict the 12.8 MB bf16 node table from L3 (gathers
// have 24x average node reuse -> want them L3-resident).

using bf16x8 = __attribute__((ext_vector_type(8))) __bf16;
using f32x4  = __attribute__((ext_vector_type(4))) float;
using u16x8  = __attribute__((ext_vector_type(8))) unsigned short;
using u16x4  = __attribute__((ext_vector_type(4))) unsigned short;

static __device__ __forceinline__ unsigned short f2b(float f) {
    return __builtin_bit_cast(unsigned short, (__bf16)f);   // RNE fp32->bf16
}
static __device__ __forceinline__ float b2f(unsigned short u) {
    return __builtin_bit_cast(float, (unsigned int)u << 16); // exact bf16->fp32
}

// ---- prep: fp32 -> bf16 for node table and W (into d_ws) ----
__global__ void prep_cvt(const float* __restrict__ nodes,
                         const float* __restrict__ W,
                         unsigned short* __restrict__ nodes_b,
                         unsigned short* __restrict__ W_b,
                         int n_node4, int n_w4) {
    int i = blockIdx.x * blockDim.x + threadIdx.x;
    int stride = gridDim.x * blockDim.x;
    int total = n_node4 + n_w4;
    for (; i < total; i += stride) {
        const float4* src; unsigned short* dst; int j;
        if (i < n_node4) { src = (const float4*)nodes; dst = nodes_b; j = i; }
        else             { src = (const float4*)W;     dst = W_b;     j = i - n_node4; }
        float4 v = src[j];
        u16x4 r;
        r[0] = f2b(v.x); r[1] = f2b(v.y); r[2] = f2b(v.z); r[3] = f2b(v.w);
        *(u16x4*)&dst[(size_t)j * 4] = r;
    }
}

// Block: 256 thr (4 waves). Wave w owns edges [tile*64 + w*16, +16).
// LDS tiles XOR-swizzled by row (chunk c stored at c ^ (row&7)).
template<int BSRC>
__global__ __launch_bounds__(256, 3) void edge_linear(
    const float* __restrict__ nodes_f,
    const unsigned short* __restrict__ nodes_b,
    const int* __restrict__ e_src,
    const int* __restrict__ e_dst,
    const float* __restrict__ Wf,
    const unsigned short* __restrict__ Wb,
    const float* __restrict__ bias,
    float* __restrict__ out,
    int E, int ntiles)
{
    __shared__ __align__(16) unsigned short Wt[128 * 128];  // 32 KiB
    __shared__ __align__(16) unsigned short At[64 * 128];   // 16 KiB
    const int tid = threadIdx.x;

    // stage W once (bf16, swizzled): B[k=d][n=o] = W[o][d]
    #pragma unroll
    for (int j = 0; j < 8; ++j) {
        int idx = j * 256 + tid;      // 2048 chunks of 8 elems
        int o = idx >> 4;             // output channel (row)
        int c = idx & 15;             // 8-elem chunk within row
        int elem = o * 128 + c * 8;
        int sw = elem ^ ((o & 7) << 3);
        if (BSRC) {
            *(u16x8*)&Wt[sw] = *(const u16x8*)&Wb[elem];
        } else {
            const float4* wp = (const float4*)&Wf[elem];
            float4 a = wp[0], b4 = wp[1];
            u16x8 r;
            r[0] = f2b(a.x);  r[1] = f2b(a.y);  r[2] = f2b(a.z);  r[3] = f2b(a.w);
            r[4] = f2b(b4.x); r[5] = f2b(b4.y); r[6] = f2b(b4.z); r[7] = f2b(b4.w);
            *(u16x8*)&Wt[sw] = r;
        }
    }
    // (covered by the first in-loop __syncthreads before any Wt read)

    const int wave = tid >> 6;
    const int lane = tid & 63;
    const int lr = lane & 15;   // A row (edge) / B col within fragment
    const int lg = lane >> 4;   // k-group: k-offset = lg*8 within 32-k fragment

    float bv[8];
    #pragma unroll
    for (int n = 0; n < 8; ++n) bv[n] = bias[n * 16 + lr];

    for (int tile = blockIdx.x; tile < ntiles; tile += gridDim.x) {
        const int ebase = tile * 64;

        // ---- cooperative A stage: 16 consecutive lanes read one 256-B row ----
        #pragma unroll
        for (int j = 0; j < 4; ++j) {
            int idx = j * 256 + tid;  // 64 edges * 16 chunks of 8 elems
            int e = idx >> 4;
            int c = idx & 15;
            int eg = ebase + e; if (eg >= E) eg = E - 1;
            int s = e_src[eg], d = e_dst[eg];
            u16x8 r;
            if (BSRC) {
                u16x8 sv = *(const u16x8*)&nodes_b[(size_t)s * 128 + c * 8];
                u16x8 dv = *(const u16x8*)&nodes_b[(size_t)d * 128 + c * 8];
                #pragma unroll
                for (int q = 0; q < 8; ++q) r[q] = f2b(b2f(sv[q]) + b2f(dv[q]));
            } else {
                const float4* sp = (const float4*)&nodes_f[(size_t)s * 128 + c * 8];
                const float4* dp = (const float4*)&nodes_f[(size_t)d * 128 + c * 8];
                float4 s0 = sp[0], s1 = sp[1], d0 = dp[0], d1 = dp[1];
                r[0] = f2b(s0.x + d0.x); r[1] = f2b(s0.y + d0.y);
                r[2] = f2b(s0.z + d0.z); r[3] = f2b(s0.w + d0.w);
                r[4] = f2b(s1.x + d1.x); r[5] = f2b(s1.y + d1.y);
                r[6] = f2b(s1.z + d1.z); r[7] = f2b(s1.w + d1.w);
            }
            *(u16x8*)&At[e * 128 + ((c ^ (e & 7)) * 8)] = r;
        }
        __syncthreads();   // A (and W, first iter) visible

        f32x4 acc[8];
        #pragma unroll
        for (int n = 0; n < 8; ++n) acc[n] = (f32x4){0.f, 0.f, 0.f, 0.f};

        const int am = wave * 16 + lr;
        #pragma unroll
        for (int ks = 0; ks < 4; ++ks) {
            bf16x8 af = *(const bf16x8*)&At[(am * 128 + ks * 32 + lg * 8) ^ ((am & 7) << 3)];
            #pragma unroll
            for (int n = 0; n < 8; ++n) {
                const int o = n * 16 + lr;
                bf16x8 bf = *(const bf16x8*)&Wt[(o * 128 + ks * 32 + lg * 8) ^ ((o & 7) << 3)];
                acc[n] = __builtin_amdgcn_mfma_f32_16x16x32_bf16(af, bf, acc[n], 0, 0, 0);
            }
        }

        // epilogue: bias + relu + NON-TEMPORAL store (keep node table in L3).
        // C/D map: col = lane&15, row = 4*lg + reg.
        const int er0 = ebase + wave * 16 + lg * 4;
        #pragma unroll
        for (int n = 0; n < 8; ++n) {
            #pragma unroll
            for (int j2 = 0; j2 < 4; ++j2) {
                const int e = er0 + j2;
                if (e < E) {
                    float v = acc[n][j2] + bv[n];
                    v = v > 0.f ? v : 0.f;
                    __builtin_nontemporal_store(v, &out[(size_t)e * 128 + n * 16 + lr]);
                }
            }
        }
        __syncthreads();   // all waves done reading At before next stage
    }
}

extern "C" void kernel_launch(void* const* d_in, const int* in_sizes, int n_in,
                              void* d_out, int out_size, void* d_ws, size_t ws_size,
                              hipStream_t stream) {
    const float* nodes = (const float*)d_in[0];
    const int*   ei    = (const int*)d_in[1];     // [2][E] int32: row0=src, row1=dst
    const float* W     = (const float*)d_in[2];   // [128][128] fp32, row-major [o][d]
    const float* bias  = (const float*)d_in[3];   // [128] fp32
    float* out = (float*)d_out;

    const int n_node = in_sizes[0];               // 50000*128
    const int E      = in_sizes[1] / 2;           // 600000
    const int n_w    = in_sizes[2];               // 128*128

    const size_t node_bytes = (size_t)n_node * 2;
    const size_t need = node_bytes + (size_t)n_w * 2;
    const int ntiles = (E + 63) / 64;             // 9375
    int blocks = ntiles < 768 ? ntiles : 768;     // 3 blocks/CU (48 KiB LDS)

    if (ws_size >= need) {
        unsigned short* nodes_b = (unsigned short*)d_ws;
        unsigned short* W_b = (unsigned short*)((char*)d_ws + node_bytes);
        int n4 = n_node / 4, w4 = n_w / 4;
        int pgrid = (n4 + w4 + 255) / 256;
        if (pgrid > 2048) pgrid = 2048;
        prep_cvt<<<pgrid, 256, 0, stream>>>(nodes, W, nodes_b, W_b, n4, w4);
        edge_linear<1><<<blocks, 256, 0, stream>>>(nodes, nodes_b, ei, ei + E,
                                                   W, W_b, bias, out, E, ntiles);
    } else {
        edge_linear<0><<<blocks, 256, 0, stream>>>(nodes, nullptr, ei, ei + E,
                                                   W, nullptr, bias, out, E, ntiles);
    }
}